// Round 1
// baseline (73.756 us; speedup 1.0000x reference)
//
#include <hip/hip_runtime.h>

// ws layout (16 bytes): [0]=loss_sum (float), [1]=trivial_sum (float),
//                       [2]=n_pos (int), [3]=n_neg (int)

__global__ void stats_kernel(const float* __restrict__ pred,
                             const int* __restrict__ target,
                             float* __restrict__ ws, int n) {
    int idx = blockIdx.x * blockDim.x + threadIdx.x;
    int stride = gridDim.x * blockDim.x;
    float trivial = 0.0f;
    int pos = 0, neg = 0;
    for (int i = idx; i < n; i += stride) {
        float p = pred[i];
        trivial += 1.0f / (p * p + 1e-5f);
        int t = target[i];
        pos += (t == 1);
        neg += (t == 0);
    }
    // wave(64) reduce
    for (int off = 32; off > 0; off >>= 1) {
        trivial += __shfl_down(trivial, off, 64);
        pos     += __shfl_down(pos, off, 64);
        neg     += __shfl_down(neg, off, 64);
    }
    __shared__ float s_t[4];
    __shared__ int   s_p[4], s_n[4];
    int lane = threadIdx.x & 63;
    int wave = threadIdx.x >> 6;
    if (lane == 0) { s_t[wave] = trivial; s_p[wave] = pos; s_n[wave] = neg; }
    __syncthreads();
    if (threadIdx.x == 0) {
        int nw = blockDim.x >> 6;
        float t = 0.0f; int p = 0, ng = 0;
        for (int w = 0; w < nw; ++w) { t += s_t[w]; p += s_p[w]; ng += s_n[w]; }
        atomicAdd(&ws[1], t);
        atomicAdd(((int*)ws) + 2, p);
        atomicAdd(((int*)ws) + 3, ng);
    }
}

// Each thread owns one i (pos candidate); loops over a j-chunk staged in LDS.
// Branch-free: non-pos i -> p_i = -1e30 (contributes 0); non-neg j -> p_j = +1e30.
__global__ void pair_kernel(const float* __restrict__ pred,
                            const int* __restrict__ target,
                            float* __restrict__ ws, int n, int jchunk) {
    __shared__ float s_pj[256];
    int tid = threadIdx.x;
    int i = blockIdx.x * 256 + tid;

    float pi = -1e30f;
    if (i < n && target[i] == 1) pi = pred[i];

    int j0 = blockIdx.y * jchunk;
    int j1 = min(j0 + jchunk, n);

    float acc = 0.0f;
    for (int jb = j0; jb < j1; jb += 256) {
        int j = jb + tid;
        float pj = 1e30f;
        if (j < j1 && target[j] == 0) pj = pred[j];
        __syncthreads();           // protect previous iteration's readers
        s_pj[tid] = pj;
        __syncthreads();
        int cnt = min(256, j1 - jb);
        #pragma unroll 8
        for (int k = 0; k < cnt; ++k) {
            acc += fmaxf(pi - s_pj[k], 0.0f);
        }
    }

    for (int off = 32; off > 0; off >>= 1)
        acc += __shfl_down(acc, off, 64);
    __shared__ float s_acc[4];
    int lane = tid & 63, wave = tid >> 6;
    if (lane == 0) s_acc[wave] = acc;
    __syncthreads();
    if (tid == 0)
        atomicAdd(&ws[0], s_acc[0] + s_acc[1] + s_acc[2] + s_acc[3]);
}

__global__ void final_kernel(const float* __restrict__ ws,
                             float* __restrict__ out, int n) {
    float loss    = ws[0];
    float trivial = ws[1];
    int pos = ((const int*)ws)[2];
    int neg = ((const int*)ws)[3];
    float N = (float)pos * (float)neg;
    out[0] = trivial / (float)n + loss / N;
}

extern "C" void kernel_launch(void* const* d_in, const int* in_sizes, int n_in,
                              void* d_out, int out_size, void* d_ws, size_t ws_size,
                              hipStream_t stream) {
    const float* pred   = (const float*)d_in[0];
    const int*   target = (const int*)d_in[1];
    int n = in_sizes[0];
    float* ws = (float*)d_ws;

    hipMemsetAsync(d_ws, 0, 16, stream);

    stats_kernel<<<32, 256, 0, stream>>>(pred, target, ws, n);

    int gx = (n + 255) / 256;          // 32 i-tiles at n=8192
    const int jchunk = 512;
    int gy = (n + jchunk - 1) / jchunk; // 16 j-chunks -> 512 blocks total
    dim3 grid(gx, gy);
    pair_kernel<<<grid, 256, 0, stream>>>(pred, target, ws, n, jchunk);

    final_kernel<<<1, 1, 0, stream>>>(ws, (float*)d_out, n);
}